// Round 4
// baseline (98.133 us; speedup 1.0000x reference)
//
#include <hip/hip_runtime.h>
#include <math.h>

// Problem constants (from reference setup_inputs)
#define BB   32    // batch
#define CC   256   // channels
#define HF   64    // feature H
#define WF   64    // feature W
#define NN   256   // grid points (16x16, step 4)
#define ROWS 16    // n-rows per sim block
#define NTILES (NN / ROWS)  // 16
#define SIMP 260   // padded sim row stride (floats), 16B-aligned, breaks bank conflicts

// ---------------------------------------------------------------------------
// Kernel A: coalesced gather, c-major outputs, norm partials. No LDS needed:
// the lane that reads point t of channel c is the lane that writes element t.
//   Dt[b][c][n], Rt[b][c][n]  (c-major)
//   nPartD/nPartR[b][cg][n]   (sumsq over the 16 channels of group cg)
//   GV[b][n]                  (grid_valid 0/1) -- cg==0 blocks only
// ---------------------------------------------------------------------------
__global__ __launch_bounds__(256) void gather_kernel(
        const float* __restrict__ fr,
        const float* __restrict__ fd,
        const float* __restrict__ vm,
        float* __restrict__ Dt,
        float* __restrict__ Rt,
        float* __restrict__ nPartD,
        float* __restrict__ nPartR,
        float* __restrict__ GV) {
    int b  = blockIdx.x >> 4;
    int cg = blockIdx.x & 15;
    int t  = threadIdx.x;
    int i  = t >> 4, j = t & 15;          // grid point (i,j) -> (y,x)=(4i,4j)

    size_t mapBase = (size_t)(b * CC + cg * 16) * (HF * WF);
    size_t ptOff   = (size_t)(4 * i) * WF + 4 * j;
    size_t outBase = (size_t)(b * CC + cg * 16) * NN + t;

    float ssd = 0.0f, ssr = 0.0f;
#pragma unroll
    for (int cc = 0; cc < 16; ++cc) {
        float vd_ = fd[mapBase + (size_t)cc * (HF * WF) + ptOff];
        float vr_ = fr[mapBase + (size_t)cc * (HF * WF) + ptOff];
        Dt[outBase + (size_t)cc * NN] = vd_;
        Rt[outBase + (size_t)cc * NN] = vr_;
        ssd = fmaf(vd_, vd_, ssd);
        ssr = fmaf(vr_, vr_, ssr);
    }
    nPartD[(size_t)(b * 16 + cg) * NN + t] = ssd;
    nPartR[(size_t)(b * 16 + cg) * NN + t] = ssr;

    if (cg == 0) {
        float v = vm[((size_t)b * 512 + 32 * i) * 512 + 32 * j];
        GV[(size_t)b * NN + t] = (v > 0.5f) ? 1.0f : 0.0f;
    }
}

// ---------------------------------------------------------------------------
// Kernel B: per (b, 16-row tile). 4x4 register-tiled GEMM:
// thread (rg=t&3, cq=t>>2) computes rows 4rg..4rg+3 x cols 4cq..4cq+3.
// Per channel: 2 float4 loads + 16 FMAs. Norms from precomputed partials.
// Epilogue: scale+mask rows into padded LDS, wave-per-row softmax/argmax.
// ---------------------------------------------------------------------------
__global__ __launch_bounds__(256) void sim_loss_kernel(
        const float* __restrict__ Dt,
        const float* __restrict__ Rt,
        const float* __restrict__ nPartD,
        const float* __restrict__ nPartR,
        const float* __restrict__ GV,
        float* __restrict__ lossPart,
        float* __restrict__ corrPart) {
    __shared__ float simLds[ROWS * SIMP];   // 16.6 KB
    __shared__ float colInv[NN];
    __shared__ float rowInv[ROWS];
    __shared__ float diagLds[ROWS];
    __shared__ float rowLoss[ROWS];
    __shared__ float rowCorr[ROWS];

    int b     = blockIdx.x >> 4;
    int tile  = blockIdx.x & (NTILES - 1);
    int nbase = tile * ROWS;
    int t     = threadIdx.x;

    // ---- row inverse norms (depth): 16 partials per row, shfl-reduced ----
    {
        int r = t >> 4, p = t & 15;   // lanes with same r are 16 consecutive
        float ss = nPartD[(size_t)(b * 16 + p) * NN + nbase + r];
#pragma unroll
        for (int off = 1; off < 16; off <<= 1) ss += __shfl_xor(ss, off, 64);
        if (p == 0) rowInv[r] = 1.0f / fmaxf(sqrtf(ss), 1e-12f);
    }
    // ---- col inverse norms (rgb): thread t sums 16 partials for col t ----
    {
        float ss = 0.0f;
#pragma unroll
        for (int p = 0; p < 16; ++p)
            ss += nPartR[(size_t)(b * 16 + p) * NN + t];
        colInv[t] = 1.0f / fmaxf(sqrtf(ss), 1e-12f);
    }

    // ---- 4x4 register-tiled GEMM over 256 channels ----
    int rg = t & 3, cq = t >> 2;
    const float* Dp = Dt + (size_t)b * CC * NN + nbase + 4 * rg;
    const float* Rp = Rt + (size_t)b * CC * NN + 4 * cq;

    float acc[4][4];
#pragma unroll
    for (int r = 0; r < 4; ++r)
#pragma unroll
        for (int q = 0; q < 4; ++q) acc[r][q] = 0.0f;

#pragma unroll 8
    for (int c = 0; c < CC; ++c) {
        float4 dv = *reinterpret_cast<const float4*>(Dp + (size_t)c * NN);
        float4 rv = *reinterpret_cast<const float4*>(Rp + (size_t)c * NN);
        float dk[4] = {dv.x, dv.y, dv.z, dv.w};
        float rk[4] = {rv.x, rv.y, rv.z, rv.w};
#pragma unroll
        for (int r = 0; r < 4; ++r)
#pragma unroll
            for (int q = 0; q < 4; ++q)
                acc[r][q] = fmaf(dk[r], rk[q], acc[r][q]);
    }

    __syncthreads();   // rowInv/colInv visible

    // ---- scale, capture diag, mask, store to LDS ----
    const float invT = 1.0f / 0.07f;
    float4 gvv = *reinterpret_cast<const float4*>(GV + (size_t)b * NN + 4 * cq);
    float gq[4] = {gvv.x, gvv.y, gvv.z, gvv.w};
    float ci[4];
    *reinterpret_cast<float4*>(ci) = *reinterpret_cast<const float4*>(&colInv[4 * cq]);

#pragma unroll
    for (int r = 0; r < 4; ++r) {
        int rl = 4 * rg + r;
        float sc = invT * rowInv[rl];
#pragma unroll
        for (int q = 0; q < 4; ++q) {
            float s = acc[r][q] * sc * ci[q];
            int col = 4 * cq + q;
            if (col == nbase + rl) diagLds[rl] = s;
            simLds[rl * SIMP + col] = (gq[q] > 0.5f) ? s : -1e30f;
        }
    }
    __syncthreads();

    // ---- one wave per row: max/argmax + sum-exp via shfl only ----
    int wv = t >> 6, ln = t & 63;
    for (int k = wv; k < ROWS; k += 4) {
        const float* row = &simLds[k * SIMP];
        float v0 = row[ln];
        float v1 = row[64 + ln];
        float v2 = row[128 + ln];
        float v3 = row[192 + ln];
        float mv = v0; int mi = ln;
        if (v1 > mv) { mv = v1; mi = ln + 64; }
        if (v2 > mv) { mv = v2; mi = ln + 128; }
        if (v3 > mv) { mv = v3; mi = ln + 192; }
#pragma unroll
        for (int off = 32; off > 0; off >>= 1) {
            float ov = __shfl_xor(mv, off, 64);
            int   oi = __shfl_xor(mi, off, 64);
            if (ov > mv || (ov == mv && oi < mi)) { mv = ov; mi = oi; }
        }
        float e = expf(v0 - mv) + expf(v1 - mv) + expf(v2 - mv) + expf(v3 - mv);
#pragma unroll
        for (int off = 32; off > 0; off >>= 1) e += __shfl_xor(e, off, 64);
        if (ln == 0) {
            float vfn = GV[(size_t)b * NN + nbase + k];
            float lz = mv + logf(e);
            rowLoss[k] = (vfn > 0.5f) ? (lz - diagLds[k]) : 0.0f;
            rowCorr[k] = (vfn > 0.5f && mi == nbase + k) ? 1.0f : 0.0f;
        }
    }
    __syncthreads();

    if (t == 0) {
        float la = 0.0f, ca = 0.0f;
#pragma unroll
        for (int k = 0; k < ROWS; ++k) { la += rowLoss[k]; ca += rowCorr[k]; }
        lossPart[blockIdx.x] = la;
        corrPart[blockIdx.x] = ca;
    }
}

// ---------------------------------------------------------------------------
// Kernel C: per-batch include / n_valid logic, final two scalars.
// ---------------------------------------------------------------------------
__global__ __launch_bounds__(256) void finalize_kernel(
        const float* __restrict__ GV,
        const float* __restrict__ lossPart,
        const float* __restrict__ corrPart,
        float* __restrict__ out) {
    __shared__ float sl[BB], sc2[BB], st2[BB];
    int t = threadIdx.x;           // 256 threads: 8 per batch
    int b = t >> 3, s = t & 7;

    float nvp = 0.0f;
    const float4* g4 = reinterpret_cast<const float4*>(GV + (size_t)b * NN);
#pragma unroll
    for (int q = 0; q < 8; ++q) {
        float4 v = g4[s * 8 + q];
        nvp += v.x + v.y + v.z + v.w;
    }
#pragma unroll
    for (int off = 1; off < 8; off <<= 1) nvp += __shfl_xor(nvp, off, 64);

    if (s == 0) {
        float lb = 0.0f, cb = 0.0f;
#pragma unroll
        for (int k = 0; k < NTILES; ++k) {
            lb += lossPart[b * NTILES + k];
            cb += corrPart[b * NTILES + k];
        }
        bool inc = (nvp >= 2.0f);
        sl[b]  = inc ? (lb / fmaxf(nvp, 1.0f)) : 0.0f;
        sc2[b] = inc ? cb : 0.0f;
        st2[b] = inc ? nvp : 0.0f;
    }
    __syncthreads();
    if (t == 0) {
        float L = 0.0f, Ccnt = 0.0f, Tcnt = 0.0f;
        for (int bb = 0; bb < BB; ++bb) { L += sl[bb]; Ccnt += sc2[bb]; Tcnt += st2[bb]; }
        float avg = L / (float)BB;
        out[0] = (Tcnt > 0.0f) ? avg : 0.0f;
        out[1] = (Tcnt > 0.0f) ? (Ccnt / fmaxf(Tcnt, 1.0f) * 100.0f) : 0.0f;
    }
}

extern "C" void kernel_launch(void* const* d_in, const int* in_sizes, int n_in,
                              void* d_out, int out_size, void* d_ws, size_t ws_size,
                              hipStream_t stream) {
    const float* fr = (const float*)d_in[0];  // fmap_rgb
    const float* fd = (const float*)d_in[1];  // fmap_depth
    // d_in[2] = projected_coords: DEAD in reference (_rgb_pos never used)
    const float* vm = (const float*)d_in[3];  // valid_mask

    float* out = (float*)d_out;
    char* ws = (char*)d_ws;

    // Workspace layout (~17.1 MB total)
    size_t featBytes = (size_t)BB * CC * NN * 4;        // 8 MB each
    size_t partBytes = (size_t)BB * 16 * NN * 4;        // 512 KB each
    float* Dt       = (float*)ws;
    float* Rt       = (float*)(ws + featBytes);
    float* nPartD   = (float*)(ws + 2 * featBytes);
    float* nPartR   = (float*)(ws + 2 * featBytes + partBytes);
    float* GV       = (float*)(ws + 2 * featBytes + 2 * partBytes);
    float* lossPart = GV + (size_t)BB * NN;             // BB*NTILES
    float* corrPart = lossPart + BB * NTILES;           // BB*NTILES

    hipLaunchKernelGGL(gather_kernel, dim3(BB * 16), dim3(256), 0, stream,
                       fr, fd, vm, Dt, Rt, nPartD, nPartR, GV);
    hipLaunchKernelGGL(sim_loss_kernel, dim3(BB * NTILES), dim3(256), 0, stream,
                       Dt, Rt, nPartD, nPartR, GV, lossPart, corrPart);
    hipLaunchKernelGGL(finalize_kernel, dim3(1), dim3(256), 0, stream,
                       GV, lossPart, corrPart, out);
}

// Round 5
// 59.316 us; speedup vs baseline: 1.6544x; 1.6544x over previous
//
#include <hip/hip_runtime.h>
#include <math.h>

// Problem constants (from reference setup_inputs)
#define BB   32    // batch
#define CC   256   // channels
#define HF   64    // feature H
#define WF   64    // feature W
#define NN   256   // grid points (16x16, step 4)
#define ROWS 16    // n-rows per sim block
#define NTILES (NN / ROWS)  // 16
#define SIMP 260   // padded sim row stride (floats)
#define NXCD 8

// ---------------------------------------------------------------------------
// Kernel A: coalesced gather, c-major outputs, norm partials.
// XCD-swizzled: XCD x owns batches 4x..4x+3 (writes land in that XCD's L2
// and, more importantly, match sim_loss's read placement).
//   Dt[b][c][n], Rt[b][c][n]  (c-major)
//   nPartD/nPartR[b][cg][n]   (sumsq over the 16 channels of group cg)
//   GV[b][n]                  (grid_valid 0/1) -- cg==0 blocks only
// ---------------------------------------------------------------------------
__global__ __launch_bounds__(256) void gather_kernel(
        const float* __restrict__ fr,
        const float* __restrict__ fd,
        const float* __restrict__ vm,
        float* __restrict__ Dt,
        float* __restrict__ Rt,
        float* __restrict__ nPartD,
        float* __restrict__ nPartR,
        float* __restrict__ GV) {
    // XCD-aware remap: blk -> (b, cg) with XCD (blk&7) owning batches 4x..4x+3
    int blk = blockIdx.x;
    int xcd = blk & (NXCD - 1);
    int r   = blk >> 3;
    int b   = xcd * 4 + (r & 3);
    int cg  = r >> 2;

    int t  = threadIdx.x;
    int i  = t >> 4, j = t & 15;          // grid point (i,j) -> (y,x)=(4i,4j)

    size_t mapBase = (size_t)(b * CC + cg * 16) * (HF * WF);
    size_t ptOff   = (size_t)(4 * i) * WF + 4 * j;
    size_t outBase = (size_t)(b * CC + cg * 16) * NN + t;

    float ssd = 0.0f, ssr = 0.0f;
#pragma unroll
    for (int cc = 0; cc < 16; ++cc) {
        float vd_ = fd[mapBase + (size_t)cc * (HF * WF) + ptOff];
        float vr_ = fr[mapBase + (size_t)cc * (HF * WF) + ptOff];
        Dt[outBase + (size_t)cc * NN] = vd_;
        Rt[outBase + (size_t)cc * NN] = vr_;
        ssd = fmaf(vd_, vd_, ssd);
        ssr = fmaf(vr_, vr_, ssr);
    }
    nPartD[(size_t)(b * 16 + cg) * NN + t] = ssd;
    nPartR[(size_t)(b * 16 + cg) * NN + t] = ssr;

    if (cg == 0) {
        float v = vm[((size_t)b * 512 + 32 * i) * 512 + 32 * j];
        GV[(size_t)b * NN + t] = (v > 0.5f) ? 1.0f : 0.0f;
    }
}

// ---------------------------------------------------------------------------
// Kernel B: per (b, 16-row tile). 4x4 register-tiled GEMM.
// XCD-swizzled identically to gather: all 16 tiles of batch b (plus its 3
// batch neighbors) run on one XCD -> per-XCD working set 2 MB < 4 MB L2.
// ---------------------------------------------------------------------------
__global__ __launch_bounds__(256) void sim_loss_kernel(
        const float* __restrict__ Dt,
        const float* __restrict__ Rt,
        const float* __restrict__ nPartD,
        const float* __restrict__ nPartR,
        const float* __restrict__ GV,
        float* __restrict__ lossPart,
        float* __restrict__ corrPart) {
    __shared__ float simLds[ROWS * SIMP];   // 16.6 KB
    __shared__ float colInv[NN];
    __shared__ float rowInv[ROWS];
    __shared__ float diagLds[ROWS];
    __shared__ float rowLoss[ROWS];
    __shared__ float rowCorr[ROWS];

    // XCD-aware remap: same bijection as gather
    int blk  = blockIdx.x;
    int xcd  = blk & (NXCD - 1);
    int rr   = blk >> 3;
    int b    = xcd * 4 + (rr & 3);
    int tile = rr >> 2;
    int nbase = tile * ROWS;
    int t     = threadIdx.x;

    // ---- row inverse norms (depth): 16 partials per row, shfl-reduced ----
    {
        int r = t >> 4, p = t & 15;
        float ss = nPartD[(size_t)(b * 16 + p) * NN + nbase + r];
#pragma unroll
        for (int off = 1; off < 16; off <<= 1) ss += __shfl_xor(ss, off, 64);
        if (p == 0) rowInv[r] = 1.0f / fmaxf(sqrtf(ss), 1e-12f);
    }
    // ---- col inverse norms (rgb): thread t sums 16 partials for col t ----
    {
        float ss = 0.0f;
#pragma unroll
        for (int p = 0; p < 16; ++p)
            ss += nPartR[(size_t)(b * 16 + p) * NN + t];
        colInv[t] = 1.0f / fmaxf(sqrtf(ss), 1e-12f);
    }

    // ---- 4x4 register-tiled GEMM over 256 channels ----
    int rg = t & 3, cq = t >> 2;
    const float* Dp = Dt + (size_t)b * CC * NN + nbase + 4 * rg;
    const float* Rp = Rt + (size_t)b * CC * NN + 4 * cq;

    float acc[4][4];
#pragma unroll
    for (int r = 0; r < 4; ++r)
#pragma unroll
        for (int q = 0; q < 4; ++q) acc[r][q] = 0.0f;

#pragma unroll 8
    for (int c = 0; c < CC; ++c) {
        float4 dv = *reinterpret_cast<const float4*>(Dp + (size_t)c * NN);
        float4 rv = *reinterpret_cast<const float4*>(Rp + (size_t)c * NN);
        float dk[4] = {dv.x, dv.y, dv.z, dv.w};
        float rk[4] = {rv.x, rv.y, rv.z, rv.w};
#pragma unroll
        for (int r = 0; r < 4; ++r)
#pragma unroll
            for (int q = 0; q < 4; ++q)
                acc[r][q] = fmaf(dk[r], rk[q], acc[r][q]);
    }

    __syncthreads();   // rowInv/colInv visible

    // ---- scale, capture diag, mask, store to LDS ----
    const float invT = 1.0f / 0.07f;
    float4 gvv = *reinterpret_cast<const float4*>(GV + (size_t)b * NN + 4 * cq);
    float gq[4] = {gvv.x, gvv.y, gvv.z, gvv.w};
    float ci[4];
    *reinterpret_cast<float4*>(ci) = *reinterpret_cast<const float4*>(&colInv[4 * cq]);

#pragma unroll
    for (int r = 0; r < 4; ++r) {
        int rl = 4 * rg + r;
        float sc = invT * rowInv[rl];
#pragma unroll
        for (int q = 0; q < 4; ++q) {
            float s = acc[r][q] * sc * ci[q];
            int col = 4 * cq + q;
            if (col == nbase + rl) diagLds[rl] = s;
            simLds[rl * SIMP + col] = (gq[q] > 0.5f) ? s : -1e30f;
        }
    }
    __syncthreads();

    // ---- one wave per row: max/argmax + sum-exp via shfl only ----
    int wv = t >> 6, ln = t & 63;
    for (int k = wv; k < ROWS; k += 4) {
        const float* row = &simLds[k * SIMP];
        float v0 = row[ln];
        float v1 = row[64 + ln];
        float v2 = row[128 + ln];
        float v3 = row[192 + ln];
        float mv = v0; int mi = ln;
        if (v1 > mv) { mv = v1; mi = ln + 64; }
        if (v2 > mv) { mv = v2; mi = ln + 128; }
        if (v3 > mv) { mv = v3; mi = ln + 192; }
#pragma unroll
        for (int off = 32; off > 0; off >>= 1) {
            float ov = __shfl_xor(mv, off, 64);
            int   oi = __shfl_xor(mi, off, 64);
            if (ov > mv || (ov == mv && oi < mi)) { mv = ov; mi = oi; }
        }
        float e = expf(v0 - mv) + expf(v1 - mv) + expf(v2 - mv) + expf(v3 - mv);
#pragma unroll
        for (int off = 32; off > 0; off >>= 1) e += __shfl_xor(e, off, 64);
        if (ln == 0) {
            float vfn = GV[(size_t)b * NN + nbase + k];
            float lz = mv + logf(e);
            rowLoss[k] = (vfn > 0.5f) ? (lz - diagLds[k]) : 0.0f;
            rowCorr[k] = (vfn > 0.5f && mi == nbase + k) ? 1.0f : 0.0f;
        }
    }
    __syncthreads();

    if (t == 0) {
        float la = 0.0f, ca = 0.0f;
#pragma unroll
        for (int k = 0; k < ROWS; ++k) { la += rowLoss[k]; ca += rowCorr[k]; }
        lossPart[(size_t)b * NTILES + tile] = la;
        corrPart[(size_t)b * NTILES + tile] = ca;
    }
}

// ---------------------------------------------------------------------------
// Kernel C: per-batch include / n_valid logic, final two scalars.
// ---------------------------------------------------------------------------
__global__ __launch_bounds__(256) void finalize_kernel(
        const float* __restrict__ GV,
        const float* __restrict__ lossPart,
        const float* __restrict__ corrPart,
        float* __restrict__ out) {
    __shared__ float sl[BB], sc2[BB], st2[BB];
    int t = threadIdx.x;           // 256 threads: 8 per batch
    int b = t >> 3, s = t & 7;

    float nvp = 0.0f;
    const float4* g4 = reinterpret_cast<const float4*>(GV + (size_t)b * NN);
#pragma unroll
    for (int q = 0; q < 8; ++q) {
        float4 v = g4[s * 8 + q];
        nvp += v.x + v.y + v.z + v.w;
    }
#pragma unroll
    for (int off = 1; off < 8; off <<= 1) nvp += __shfl_xor(nvp, off, 64);

    if (s == 0) {
        float lb = 0.0f, cb = 0.0f;
#pragma unroll
        for (int k = 0; k < NTILES; ++k) {
            lb += lossPart[b * NTILES + k];
            cb += corrPart[b * NTILES + k];
        }
        bool inc = (nvp >= 2.0f);
        sl[b]  = inc ? (lb / fmaxf(nvp, 1.0f)) : 0.0f;
        sc2[b] = inc ? cb : 0.0f;
        st2[b] = inc ? nvp : 0.0f;
    }
    __syncthreads();
    if (t == 0) {
        float L = 0.0f, Ccnt = 0.0f, Tcnt = 0.0f;
        for (int bb = 0; bb < BB; ++bb) { L += sl[bb]; Ccnt += sc2[bb]; Tcnt += st2[bb]; }
        float avg = L / (float)BB;
        out[0] = (Tcnt > 0.0f) ? avg : 0.0f;
        out[1] = (Tcnt > 0.0f) ? (Ccnt / fmaxf(Tcnt, 1.0f) * 100.0f) : 0.0f;
    }
}

extern "C" void kernel_launch(void* const* d_in, const int* in_sizes, int n_in,
                              void* d_out, int out_size, void* d_ws, size_t ws_size,
                              hipStream_t stream) {
    const float* fr = (const float*)d_in[0];  // fmap_rgb
    const float* fd = (const float*)d_in[1];  // fmap_depth
    // d_in[2] = projected_coords: DEAD in reference (_rgb_pos never used)
    const float* vm = (const float*)d_in[3];  // valid_mask

    float* out = (float*)d_out;
    char* ws = (char*)d_ws;

    // Workspace layout (~17.1 MB total)
    size_t featBytes = (size_t)BB * CC * NN * 4;        // 8 MB each
    size_t partBytes = (size_t)BB * 16 * NN * 4;        // 512 KB each
    float* Dt       = (float*)ws;
    float* Rt       = (float*)(ws + featBytes);
    float* nPartD   = (float*)(ws + 2 * featBytes);
    float* nPartR   = (float*)(ws + 2 * featBytes + partBytes);
    float* GV       = (float*)(ws + 2 * featBytes + 2 * partBytes);
    float* lossPart = GV + (size_t)BB * NN;             // BB*NTILES
    float* corrPart = lossPart + BB * NTILES;           // BB*NTILES

    hipLaunchKernelGGL(gather_kernel, dim3(BB * 16), dim3(256), 0, stream,
                       fr, fd, vm, Dt, Rt, nPartD, nPartR, GV);
    hipLaunchKernelGGL(sim_loss_kernel, dim3(BB * NTILES), dim3(256), 0, stream,
                       Dt, Rt, nPartD, nPartR, GV, lossPart, corrPart);
    hipLaunchKernelGGL(finalize_kernel, dim3(1), dim3(256), 0, stream,
                       GV, lossPart, corrPart, out);
}

// Round 6
// 38.749 us; speedup vs baseline: 2.5325x; 1.5308x over previous
//
#include <hip/hip_runtime.h>
#include <math.h>

// Problem constants (from reference setup_inputs)
#define BB   32    // batch
#define CC   256   // channels
#define HF   64    // feature H
#define WF   64    // feature W
#define NN   256   // grid points (16x16, step 4)
#define MROWS 32   // rows per sim block (strip)
#define NSTRIP (NN / MROWS)  // 8 strips per batch
#define SIMP 260   // padded sim row stride (floats)
#define NXCD 8

typedef __attribute__((ext_vector_type(8))) short    bf16x8;
typedef __attribute__((ext_vector_type(4))) float    f32x4;
typedef __attribute__((ext_vector_type(8))) unsigned short u16x8;

__device__ inline unsigned short f2bf(float f) {   // round-to-nearest-even
    unsigned u = __float_as_uint(f);
    unsigned r = u + 0x7FFFu + ((u >> 16) & 1u);
    return (unsigned short)(r >> 16);
}

// ---------------------------------------------------------------------------
// Kernel A: coalesced gather -> bf16 features (n-major) + f32 norm partials.
//   Dbf/Rbf[b][n][c]  (bf16, row = one grid point's 256 channels = 512 B)
//   nPartD/nPartR[b][cg][n]  (f32 sumsq over 16-channel group cg)
//   GV[b][n]  (grid_valid 0/1) -- cg==0 blocks only
// XCD-swizzled like sim so producer/consumer share an L2.
// ---------------------------------------------------------------------------
__global__ __launch_bounds__(256) void gather_kernel(
        const float* __restrict__ fr,
        const float* __restrict__ fd,
        const float* __restrict__ vm,
        unsigned short* __restrict__ Dbf,
        unsigned short* __restrict__ Rbf,
        float* __restrict__ nPartD,
        float* __restrict__ nPartR,
        float* __restrict__ GV) {
    int blk = blockIdx.x;
    int xcd = blk & (NXCD - 1);
    int r   = blk >> 3;
    int b   = xcd * 4 + (r & 3);
    int cg  = r >> 2;

    int t = threadIdx.x;
    int i = t >> 4, j = t & 15;           // grid point (i,j) -> (y,x)=(4i,4j)

    size_t mapBase = (size_t)(b * CC + cg * 16) * (HF * WF);
    size_t ptOff   = (size_t)(4 * i) * WF + 4 * j;

    float ssd = 0.0f, ssr = 0.0f;
    unsigned short dbuf[16], rbuf[16];
#pragma unroll
    for (int cc = 0; cc < 16; ++cc) {
        float vd_ = fd[mapBase + (size_t)cc * (HF * WF) + ptOff];
        float vr_ = fr[mapBase + (size_t)cc * (HF * WF) + ptOff];
        dbuf[cc] = f2bf(vd_);
        rbuf[cc] = f2bf(vr_);
        ssd = fmaf(vd_, vd_, ssd);
        ssr = fmaf(vr_, vr_, ssr);
    }
    unsigned short* dDst = Dbf + ((size_t)(b * NN + t) * CC + cg * 16);
    unsigned short* rDst = Rbf + ((size_t)(b * NN + t) * CC + cg * 16);
    *reinterpret_cast<u16x8*>(dDst)     = *reinterpret_cast<u16x8*>(&dbuf[0]);
    *reinterpret_cast<u16x8*>(dDst + 8) = *reinterpret_cast<u16x8*>(&dbuf[8]);
    *reinterpret_cast<u16x8*>(rDst)     = *reinterpret_cast<u16x8*>(&rbuf[0]);
    *reinterpret_cast<u16x8*>(rDst + 8) = *reinterpret_cast<u16x8*>(&rbuf[8]);

    nPartD[(size_t)(b * 16 + cg) * NN + t] = ssd;
    nPartR[(size_t)(b * 16 + cg) * NN + t] = ssr;

    if (cg == 0) {
        float v = vm[((size_t)b * 512 + 32 * i) * 512 + 32 * j];
        GV[(size_t)b * NN + t] = (v > 0.5f) ? 1.0f : 0.0f;
    }
}

// ---------------------------------------------------------------------------
// Kernel B: MFMA sim. Block = (b, 32-row strip), 4 waves.
// Wave w computes rows [nbase, nbase+32) x cols [w*64, w*64+64) via
// 2(M) x 4(N) tiles of mfma_f32_16x16x32_bf16, 8 K-steps over 256 channels.
// A and B fragments both load 8 consecutive channels per lane (identical
// lane->k maps => dot correct under any HW k-permutation).
// C/D layout (m89-verified): col = lane&15, row = (lane>>4)*4 + reg.
// Epilogue: scale by invT*rowInv*colInv, mask, padded-LDS wave-per-row
// softmax/argmax (proven structure from earlier rounds).
// ---------------------------------------------------------------------------
__global__ __launch_bounds__(256) void sim_loss_kernel(
        const unsigned short* __restrict__ Dbf,
        const unsigned short* __restrict__ Rbf,
        const float* __restrict__ nPartD,
        const float* __restrict__ nPartR,
        const float* __restrict__ GV,
        float* __restrict__ lossPart,
        float* __restrict__ corrPart) {
    __shared__ float simLds[MROWS * SIMP];   // 33.3 KB
    __shared__ float colInv[NN];
    __shared__ float validF[NN];
    __shared__ float rowInv[MROWS];
    __shared__ float diagLds[MROWS];
    __shared__ float rowLoss[MROWS];
    __shared__ float rowCorr[MROWS];

    int blk   = blockIdx.x;                  // 256 blocks
    int xcd   = blk & (NXCD - 1);
    int rr    = blk >> 3;
    int b     = xcd * 4 + (rr & 3);
    int strip = rr >> 2;
    int nbase = strip * MROWS;

    int t  = threadIdx.x;
    int w  = t >> 6;
    int l  = t & 63;
    int lg = l >> 4, lr = l & 15;

    // ---- norms + validity into LDS ----
    {
        float ss = 0.0f;
#pragma unroll
        for (int p = 0; p < 16; ++p) ss += nPartR[(size_t)(b * 16 + p) * NN + t];
        colInv[t] = 1.0f / fmaxf(sqrtf(ss), 1e-12f);
        validF[t] = GV[(size_t)b * NN + t];
    }
    if (t < MROWS) {
        float ss = 0.0f;
#pragma unroll
        for (int p = 0; p < 16; ++p) ss += nPartD[(size_t)(b * 16 + p) * NN + nbase + t];
        rowInv[t] = 1.0f / fmaxf(sqrtf(ss), 1e-12f);
    }
    __syncthreads();

    // ---- MFMA GEMM ----
    const unsigned short* Dp = Dbf + (size_t)(b * NN + nbase) * CC;
    const unsigned short* Rp = Rbf + (size_t)b * NN * CC;

    f32x4 acc[2][4] = {};

#pragma unroll
    for (int ks = 0; ks < 8; ++ks) {
        int coff = ks * 32 + lg * 8;
        bf16x8 a0 = *reinterpret_cast<const bf16x8*>(Dp + (size_t)(lr)      * CC + coff);
        bf16x8 a1 = *reinterpret_cast<const bf16x8*>(Dp + (size_t)(16 + lr) * CC + coff);
        bf16x8 b0 = *reinterpret_cast<const bf16x8*>(Rp + (size_t)(w * 64 +  0 + lr) * CC + coff);
        bf16x8 b1 = *reinterpret_cast<const bf16x8*>(Rp + (size_t)(w * 64 + 16 + lr) * CC + coff);
        bf16x8 b2 = *reinterpret_cast<const bf16x8*>(Rp + (size_t)(w * 64 + 32 + lr) * CC + coff);
        bf16x8 b3 = *reinterpret_cast<const bf16x8*>(Rp + (size_t)(w * 64 + 48 + lr) * CC + coff);
        acc[0][0] = __builtin_amdgcn_mfma_f32_16x16x32_bf16(a0, b0, acc[0][0], 0, 0, 0);
        acc[0][1] = __builtin_amdgcn_mfma_f32_16x16x32_bf16(a0, b1, acc[0][1], 0, 0, 0);
        acc[0][2] = __builtin_amdgcn_mfma_f32_16x16x32_bf16(a0, b2, acc[0][2], 0, 0, 0);
        acc[0][3] = __builtin_amdgcn_mfma_f32_16x16x32_bf16(a0, b3, acc[0][3], 0, 0, 0);
        acc[1][0] = __builtin_amdgcn_mfma_f32_16x16x32_bf16(a1, b0, acc[1][0], 0, 0, 0);
        acc[1][1] = __builtin_amdgcn_mfma_f32_16x16x32_bf16(a1, b1, acc[1][1], 0, 0, 0);
        acc[1][2] = __builtin_amdgcn_mfma_f32_16x16x32_bf16(a1, b2, acc[1][2], 0, 0, 0);
        acc[1][3] = __builtin_amdgcn_mfma_f32_16x16x32_bf16(a1, b3, acc[1][3], 0, 0, 0);
    }

    // ---- epilogue: scale, diag capture, mask, store rows to LDS ----
    const float invT = 1.0f / 0.07f;
#pragma unroll
    for (int mi = 0; mi < 2; ++mi) {
#pragma unroll
        for (int ni = 0; ni < 4; ++ni) {
            int col = w * 64 + ni * 16 + lr;
            float ci = colInv[col];
            float gv = validF[col];
#pragma unroll
            for (int reg = 0; reg < 4; ++reg) {
                int lrow = mi * 16 + lg * 4 + reg;
                float s = acc[mi][ni][reg] * invT * rowInv[lrow] * ci;
                if (col == nbase + lrow) diagLds[lrow] = s;
                simLds[lrow * SIMP + col] = (gv > 0.5f) ? s : -1e30f;
            }
        }
    }
    __syncthreads();

    // ---- one wave per row: max/argmax + sum-exp via shfl only ----
    for (int k = w; k < MROWS; k += 4) {
        const float* row = &simLds[k * SIMP];
        float v0 = row[l];
        float v1 = row[64 + l];
        float v2 = row[128 + l];
        float v3 = row[192 + l];
        float mv = v0; int mi = l;
        if (v1 > mv) { mv = v1; mi = l + 64; }
        if (v2 > mv) { mv = v2; mi = l + 128; }
        if (v3 > mv) { mv = v3; mi = l + 192; }
#pragma unroll
        for (int off = 32; off > 0; off >>= 1) {
            float ov = __shfl_xor(mv, off, 64);
            int   oi = __shfl_xor(mi, off, 64);
            if (ov > mv || (ov == mv && oi < mi)) { mv = ov; mi = oi; }
        }
        float e = expf(v0 - mv) + expf(v1 - mv) + expf(v2 - mv) + expf(v3 - mv);
#pragma unroll
        for (int off = 32; off > 0; off >>= 1) e += __shfl_xor(e, off, 64);
        if (l == 0) {
            float vfn = validF[nbase + k];
            float lz = mv + logf(e);
            rowLoss[k] = (vfn > 0.5f) ? (lz - diagLds[k]) : 0.0f;
            rowCorr[k] = (vfn > 0.5f && mi == nbase + k) ? 1.0f : 0.0f;
        }
    }
    __syncthreads();

    if (t == 0) {
        float la = 0.0f, ca = 0.0f;
#pragma unroll
        for (int k = 0; k < MROWS; ++k) { la += rowLoss[k]; ca += rowCorr[k]; }
        lossPart[(size_t)b * NSTRIP + strip] = la;
        corrPart[(size_t)b * NSTRIP + strip] = ca;
    }
}

// ---------------------------------------------------------------------------
// Kernel C: per-batch include / n_valid logic, final two scalars.
// ---------------------------------------------------------------------------
__global__ __launch_bounds__(256) void finalize_kernel(
        const float* __restrict__ GV,
        const float* __restrict__ lossPart,
        const float* __restrict__ corrPart,
        float* __restrict__ out) {
    __shared__ float sl[BB], sc2[BB], st2[BB];
    int t = threadIdx.x;           // 256 threads: 8 per batch
    int b = t >> 3, s = t & 7;

    float nvp = 0.0f;
    const float4* g4 = reinterpret_cast<const float4*>(GV + (size_t)b * NN);
#pragma unroll
    for (int q = 0; q < 8; ++q) {
        float4 v = g4[s * 8 + q];
        nvp += v.x + v.y + v.z + v.w;
    }
#pragma unroll
    for (int off = 1; off < 8; off <<= 1) nvp += __shfl_xor(nvp, off, 64);

    if (s == 0) {
        float lb = 0.0f, cb = 0.0f;
#pragma unroll
        for (int k = 0; k < NSTRIP; ++k) {
            lb += lossPart[b * NSTRIP + k];
            cb += corrPart[b * NSTRIP + k];
        }
        bool inc = (nvp >= 2.0f);
        sl[b]  = inc ? (lb / fmaxf(nvp, 1.0f)) : 0.0f;
        sc2[b] = inc ? cb : 0.0f;
        st2[b] = inc ? nvp : 0.0f;
    }
    __syncthreads();
    if (t == 0) {
        float L = 0.0f, Ccnt = 0.0f, Tcnt = 0.0f;
        for (int bb = 0; bb < BB; ++bb) { L += sl[bb]; Ccnt += sc2[bb]; Tcnt += st2[bb]; }
        float avg = L / (float)BB;
        out[0] = (Tcnt > 0.0f) ? avg : 0.0f;
        out[1] = (Tcnt > 0.0f) ? (Ccnt / fmaxf(Tcnt, 1.0f) * 100.0f) : 0.0f;
    }
}

extern "C" void kernel_launch(void* const* d_in, const int* in_sizes, int n_in,
                              void* d_out, int out_size, void* d_ws, size_t ws_size,
                              hipStream_t stream) {
    const float* fr = (const float*)d_in[0];  // fmap_rgb
    const float* fd = (const float*)d_in[1];  // fmap_depth
    // d_in[2] = projected_coords: DEAD in reference (_rgb_pos never used)
    const float* vm = (const float*)d_in[3];  // valid_mask

    float* out = (float*)d_out;
    char* ws = (char*)d_ws;

    // Workspace layout (~9.1 MB total)
    size_t featBytes = (size_t)BB * NN * CC * 2;        // 4 MB each (bf16)
    size_t partBytes = (size_t)BB * 16 * NN * 4;        // 512 KB each
    unsigned short* Dbf = (unsigned short*)ws;
    unsigned short* Rbf = (unsigned short*)(ws + featBytes);
    float* nPartD   = (float*)(ws + 2 * featBytes);
    float* nPartR   = (float*)(ws + 2 * featBytes + partBytes);
    float* GV       = (float*)(ws + 2 * featBytes + 2 * partBytes);
    float* lossPart = GV + (size_t)BB * NN;             // BB*NSTRIP
    float* corrPart = lossPart + BB * NSTRIP;           // BB*NSTRIP

    hipLaunchKernelGGL(gather_kernel, dim3(BB * 16), dim3(256), 0, stream,
                       fr, fd, vm, Dbf, Rbf, nPartD, nPartR, GV);
    hipLaunchKernelGGL(sim_loss_kernel, dim3(BB * NSTRIP), dim3(256), 0, stream,
                       Dbf, Rbf, nPartD, nPartR, GV, lossPart, corrPart);
    hipLaunchKernelGGL(finalize_kernel, dim3(1), dim3(256), 0, stream,
                       GV, lossPart, corrPart, out);
}